// Round 1
// baseline (38.615 us; speedup 1.0000x reference)
//
#include <hip/hip_runtime.h>
#include <hip/hip_bf16.h>

// EdgeConv: B=8, C=64, N=4096, K=16, O=64
// h[b,n,k,:] = relu(x_i @ (Wa-Wb) + x_j @ Wb + bias); out = max_k h
// Implemented as K=128 augmented-row MFMA: A row k = [x_i | x_j_k], B = Wmod[128][64].

#define BB 8
#define CC 64
#define NN 4096
#define KK 16
#define OO 64

typedef __bf16 bf16x8 __attribute__((ext_vector_type(8)));
typedef float f32x4 __attribute__((ext_vector_type(4)));

union Frag { int4 i; bf16x8 v; };

static constexpr size_t XTB_ELEMS = (size_t)BB * NN * CC;   // 2,097,152 bf16 = 4 MB
static constexpr size_t WFRAG_ELEMS = 4 * 4 * 64 * 8;       // 8192 bf16 = 16 KB

// Build Wmod = [[Wa - Wb],[Wb]] (128x64) directly in MFMA B-fragment order:
// frag idx = ((s*4 + ot)*64 + lane)*8 + j holds Wmod[s*32 + (lane>>4)*8 + j][ot*16 + (lane&15)]
__global__ __launch_bounds__(256) void prep_w(const float* __restrict__ W,
                                              __hip_bfloat16* __restrict__ wfrag) {
    int t = threadIdx.x;
    for (int idx = t; idx < (int)WFRAG_ELEMS; idx += 256) {
        int j = idx & 7, lane = (idx >> 3) & 63, ot = (idx >> 9) & 3, s = idx >> 11;
        int kdim = s * 32 + (lane >> 4) * 8 + j;
        int o = ot * 16 + (lane & 15);
        float v = (kdim < 64) ? (W[kdim * OO + o] - W[(kdim + 64) * OO + o])
                              : W[kdim * OO + o];
        wfrag[idx] = __float2bfloat16(v);
    }
}

// Transpose+cast x [B,C,N] f32 -> xtb [B,N,C] bf16 (node-major so gathers are contiguous)
__global__ __launch_bounds__(256) void prep_x(const float* __restrict__ x,
                                              __hip_bfloat16* __restrict__ xtb) {
    __shared__ float tile[64][65];
    int b = blockIdx.x >> 6;            // 64 n-tiles per batch
    int n0 = (blockIdx.x & 63) << 6;
    int t = threadIdx.x;
    const float* xb = x + (size_t)b * CC * NN;
    #pragma unroll
    for (int it = 0; it < 16; ++it) {
        int idx = it * 256 + t;
        int c = idx >> 6, nn = idx & 63;
        tile[c][nn] = xb[c * NN + n0 + nn];       // coalesced along n
    }
    __syncthreads();
    __hip_bfloat16* xo = xtb + ((size_t)b * NN + n0) * CC;
    #pragma unroll
    for (int it = 0; it < 16; ++it) {
        int idx = it * 256 + t;
        int nl = idx >> 6, c = idx & 63;
        xo[nl * CC + c] = __float2bfloat16(tile[c][nl]);  // coalesced along c
    }
}

// Main: one wave per node. 16 edges = 16 MFMA rows. 4 o-tiles x 4 K-steps.
__global__ __launch_bounds__(256) void edgeconv_main(
    const int* __restrict__ ei, const float* __restrict__ bias,
    const __hip_bfloat16* __restrict__ xtb, const __hip_bfloat16* __restrict__ wfrag,
    float* __restrict__ out) {
    __shared__ float otile[64][33];
    int t = threadIdx.x;
    int w = t >> 6, l = t & 63;
    int b = blockIdx.x >> 7;            // 128 32-node tiles per batch
    int n0 = (blockIdx.x & 127) << 5;

    // W fragments: lane l's 8 bf16 for (s, ot) are contiguous -> one dwordx4 each
    Frag wf[4][4];
    const int4* wf4 = (const int4*)wfrag;
    #pragma unroll
    for (int s = 0; s < 4; ++s)
        #pragma unroll
        for (int ot = 0; ot < 4; ++ot)
            wf[s][ot].i = wf4[(s * 4 + ot) * 64 + l];

    float bv[4];
    #pragma unroll
    for (int ot = 0; ot < 4; ++ot) bv[ot] = bias[ot * 16 + (l & 15)];

    const int* srcp = ei + (size_t)b * NN * KK;                 // ei[0][b]
    const int4* xt4 = (const int4*)(xtb + (size_t)b * NN * CC); // 8 bf16 per int4

    int lg = l >> 4;   // K-chunk group 0..3
    int le = l & 15;   // edge index / output col

    for (int i = 0; i < 8; ++i) {
        int nl = w * 8 + i;
        int n = n0 + nl;
        Frag a0, a1, a2, a3;
        a0.i = xt4[n * 8 + lg];          // x_i elems [lg*8, lg*8+8)    (kdim 0..32)
        a1.i = xt4[n * 8 + 4 + lg];      // x_i elems 32+[lg*8..)       (kdim 32..64)
        int v = srcp[n * KK + le];       // neighbor id (per-batch)
        a2.i = xt4[v * 8 + lg];          // x_j elems                   (kdim 64..96)
        a3.i = xt4[v * 8 + 4 + lg];      //                             (kdim 96..128)

        f32x4 acc[4];
        #pragma unroll
        for (int ot = 0; ot < 4; ++ot) acc[ot] = f32x4{bv[ot], bv[ot], bv[ot], bv[ot]};

        #pragma unroll
        for (int ot = 0; ot < 4; ++ot) {
            acc[ot] = __builtin_amdgcn_mfma_f32_16x16x32_bf16(a0.v, wf[0][ot].v, acc[ot], 0, 0, 0);
            acc[ot] = __builtin_amdgcn_mfma_f32_16x16x32_bf16(a1.v, wf[1][ot].v, acc[ot], 0, 0, 0);
            acc[ot] = __builtin_amdgcn_mfma_f32_16x16x32_bf16(a2.v, wf[2][ot].v, acc[ot], 0, 0, 0);
            acc[ot] = __builtin_amdgcn_mfma_f32_16x16x32_bf16(a3.v, wf[3][ot].v, acc[ot], 0, 0, 0);
        }

        // D layout: col = lane&15 (=o), row = (lane>>4)*4 + reg (=edge). Max over 16 edges:
        #pragma unroll
        for (int ot = 0; ot < 4; ++ot) {
            float r = fmaxf(fmaxf(acc[ot][0], acc[ot][1]), fmaxf(acc[ot][2], acc[ot][3]));
            r = fmaxf(r, __shfl_xor(r, 16));
            r = fmaxf(r, __shfl_xor(r, 32));
            r = fmaxf(r, 0.0f);            // relu commutes with max
            if (l < 16) otile[ot * 16 + l][nl] = r;
        }
    }
    __syncthreads();
    // Coalesced write of the 64x32 tile to out[b][o][n]
    float* ob = out + (size_t)b * OO * NN;
    #pragma unroll
    for (int it = 0; it < 8; ++it) {
        int idx = it * 256 + t;
        int o = idx >> 5, nn = idx & 31;
        ob[(size_t)o * NN + n0 + nn] = otile[o][nn];
    }
}

extern "C" void kernel_launch(void* const* d_in, const int* in_sizes, int n_in,
                              void* d_out, int out_size, void* d_ws, size_t ws_size,
                              hipStream_t stream) {
    const float* x    = (const float*)d_in[0];   // [B,C,N,1] f32
    const int*   ei   = (const int*)d_in[1];     // [2,B,N,K] i32
    const float* W    = (const float*)d_in[2];   // [128,64] f32
    const float* bias = (const float*)d_in[3];   // [64] f32
    float* out = (float*)d_out;                  // [B,O,N,1] f32

    __hip_bfloat16* xtb   = (__hip_bfloat16*)d_ws;           // 4 MB
    __hip_bfloat16* wfrag = xtb + XTB_ELEMS;                 // +16 KB

    hipLaunchKernelGGL(prep_w, dim3(1), dim3(256), 0, stream, W, wfrag);
    hipLaunchKernelGGL(prep_x, dim3(BB * (NN / 64)), dim3(256), 0, stream, x, xtb);
    hipLaunchKernelGGL(edgeconv_main, dim3(BB * (NN / 32)), dim3(256), 0, stream,
                       ei, bias, xtb, wfrag, out);
}

// Round 2
// 30.897 us; speedup vs baseline: 1.2498x; 1.2498x over previous
//
#include <hip/hip_runtime.h>
#include <hip/hip_bf16.h>

// EdgeConv: B=8, C=64, N=4096, K=16, O=64
// h[b,n,k,:] = relu(x_i @ (Wa-Wb) + x_j @ Wb + bias); out = max_k h
// K=128 augmented-row MFMA: A row e = [x_i | x_j_e], B = Wmod[128][64].

#define BB 8
#define CC 64
#define NN 4096
#define KK 16
#define OO 64

typedef __bf16 bf16x8 __attribute__((ext_vector_type(8)));
typedef float f32x4 __attribute__((ext_vector_type(4)));

union Frag { int4 i; bf16x8 v; };

static constexpr size_t XTB_ELEMS = (size_t)BB * NN * CC;   // 4 MB bf16
static constexpr size_t WFRAG_ELEMS = 4 * 4 * 64 * 8;       // 16 KB bf16
static constexpr int NXT = BB * (NN / 64);                  // 512 x-transpose blocks

// Fused prep: blocks [0,512) transpose+cast x -> xtb [B,N,C] bf16;
// block 512 builds Wmod=[[Wa-Wb],[Wb]] in MFMA B-fragment order.
__global__ __launch_bounds__(256) void prep(const float* __restrict__ x,
                                            const float* __restrict__ W,
                                            __hip_bfloat16* __restrict__ xtb,
                                            __hip_bfloat16* __restrict__ wfrag) {
    int t = threadIdx.x;
    if (blockIdx.x == NXT) {
        for (int idx = t; idx < (int)WFRAG_ELEMS; idx += 256) {
            int j = idx & 7, lane = (idx >> 3) & 63, ot = (idx >> 9) & 3, s = idx >> 11;
            int kdim = s * 32 + (lane >> 4) * 8 + j;
            int o = ot * 16 + (lane & 15);
            float v = (kdim < 64) ? (W[kdim * OO + o] - W[(kdim + 64) * OO + o])
                                  : W[kdim * OO + o];
            wfrag[idx] = __float2bfloat16(v);
        }
        return;
    }
    __shared__ float tile[64][65];
    int b = blockIdx.x >> 6;
    int n0 = (blockIdx.x & 63) << 6;
    const float* xb = x + (size_t)b * CC * NN;
    #pragma unroll
    for (int it = 0; it < 16; ++it) {
        int idx = it * 256 + t;
        int c = idx >> 6, nn = idx & 63;
        tile[c][nn] = xb[c * NN + n0 + nn];                 // coalesced along n
    }
    __syncthreads();
    __hip_bfloat16* xo = xtb + ((size_t)b * NN + n0) * CC;
    #pragma unroll
    for (int it = 0; it < 16; ++it) {
        int idx = it * 256 + t;
        int nl = idx >> 6, c = idx & 63;
        xo[nl * CC + c] = __float2bfloat16(tile[c][nl]);    // coalesced along c
    }
}

// Main: one wave per 8 nodes, 2-deep pipelined. 16 edges = 16 MFMA rows.
__global__ __launch_bounds__(256, 3) void edgeconv_main(
    const int* __restrict__ ei, const float* __restrict__ bias,
    const __hip_bfloat16* __restrict__ xtb, const __hip_bfloat16* __restrict__ wfrag,
    float* __restrict__ out) {
    __shared__ float otile[64][33];
    int t = threadIdx.x;
    int w = t >> 6, l = t & 63;
    int b = blockIdx.x >> 7;            // 128 32-node tiles per batch
    int n0 = (blockIdx.x & 127) << 5;

    // W fragments: lane l's 8 bf16 for (s, ot) contiguous -> one dwordx4 each (64 VGPR)
    Frag wf[4][4];
    const int4* wf4 = (const int4*)wfrag;
    #pragma unroll
    for (int s = 0; s < 4; ++s)
        #pragma unroll
        for (int ot = 0; ot < 4; ++ot)
            wf[s][ot].i = wf4[(s * 4 + ot) * 64 + l];

    float bv[4];
    #pragma unroll
    for (int ot = 0; ot < 4; ++ot) bv[ot] = bias[ot * 16 + (l & 15)];

    const int* srcp = ei + (size_t)b * NN * KK;                 // ei[0][b]
    const int4* xt4 = (const int4*)(xtb + (size_t)b * NN * CC); // 8 bf16 per int4

    int lg = l >> 4;   // K-chunk group 0..3
    int le = l & 15;   // edge index / output col
    int nbase = n0 + w * 8;

    // Prefetch all 8 edge indices up front (independent loads)
    int vidx[8];
    #pragma unroll
    for (int i = 0; i < 8; ++i) vidx[i] = srcp[(nbase + i) * KK + le];

    // 2-deep A-fragment pipeline, all indices compile-time under full unroll
    Frag a[2][4];
    {
        int n = nbase;
        a[0][0].i = xt4[n * 8 + lg];
        a[0][1].i = xt4[n * 8 + 4 + lg];
        int v = vidx[0];
        a[0][2].i = xt4[v * 8 + lg];
        a[0][3].i = xt4[v * 8 + 4 + lg];
    }
    #pragma unroll
    for (int i = 0; i < 8; ++i) {
        if (i < 7) {
            int n = nbase + i + 1;
            int v = vidx[i + 1];
            a[(i + 1) & 1][0].i = xt4[n * 8 + lg];
            a[(i + 1) & 1][1].i = xt4[n * 8 + 4 + lg];
            a[(i + 1) & 1][2].i = xt4[v * 8 + lg];
            a[(i + 1) & 1][3].i = xt4[v * 8 + 4 + lg];
        }
        Frag* ac = a[i & 1];

        f32x4 acc[4];
        #pragma unroll
        for (int ot = 0; ot < 4; ++ot) acc[ot] = f32x4{bv[ot], bv[ot], bv[ot], bv[ot]};

        #pragma unroll
        for (int ot = 0; ot < 4; ++ot) {
            acc[ot] = __builtin_amdgcn_mfma_f32_16x16x32_bf16(ac[0].v, wf[0][ot].v, acc[ot], 0, 0, 0);
            acc[ot] = __builtin_amdgcn_mfma_f32_16x16x32_bf16(ac[1].v, wf[1][ot].v, acc[ot], 0, 0, 0);
            acc[ot] = __builtin_amdgcn_mfma_f32_16x16x32_bf16(ac[2].v, wf[2][ot].v, acc[ot], 0, 0, 0);
            acc[ot] = __builtin_amdgcn_mfma_f32_16x16x32_bf16(ac[3].v, wf[3][ot].v, acc[ot], 0, 0, 0);
        }

        // D layout: col = lane&15 (=o), row = (lane>>4)*4 + reg (=edge). Max over 16 edges.
        int nl = w * 8 + i;
        #pragma unroll
        for (int ot = 0; ot < 4; ++ot) {
            float r = fmaxf(fmaxf(acc[ot][0], acc[ot][1]), fmaxf(acc[ot][2], acc[ot][3]));
            r = fmaxf(r, __shfl_xor(r, 16));
            r = fmaxf(r, __shfl_xor(r, 32));
            r = fmaxf(r, 0.0f);            // relu commutes with max
            if (l < 16) otile[ot * 16 + l][nl] = r;
        }
    }
    __syncthreads();
    // Coalesced write of the 64x32 tile to out[b][o][n]
    float* ob = out + (size_t)b * OO * NN;
    #pragma unroll
    for (int it = 0; it < 8; ++it) {
        int idx = it * 256 + t;
        int o = idx >> 5, nn = idx & 31;
        ob[(size_t)o * NN + n0 + nn] = otile[o][nn];
    }
}

extern "C" void kernel_launch(void* const* d_in, const int* in_sizes, int n_in,
                              void* d_out, int out_size, void* d_ws, size_t ws_size,
                              hipStream_t stream) {
    const float* x    = (const float*)d_in[0];   // [B,C,N,1] f32
    const int*   ei   = (const int*)d_in[1];     // [2,B,N,K] i32
    const float* W    = (const float*)d_in[2];   // [128,64] f32
    const float* bias = (const float*)d_in[3];   // [64] f32
    float* out = (float*)d_out;                  // [B,O,N,1] f32

    __hip_bfloat16* xtb   = (__hip_bfloat16*)d_ws;           // 4 MB
    __hip_bfloat16* wfrag = xtb + XTB_ELEMS;                 // +16 KB

    hipLaunchKernelGGL(prep, dim3(NXT + 1), dim3(256), 0, stream, x, W, xtb, wfrag);
    hipLaunchKernelGGL(edgeconv_main, dim3(BB * (NN / 32)), dim3(256), 0, stream,
                       ei, bias, xtb, wfrag, out);
}